// Round 7
// baseline (520.200 us; speedup 1.0000x reference)
//
#include <hip/hip_runtime.h>
#include <hip/hip_bf16.h>
#include <stdint.h>
#include <stddef.h>

#define NN 50000
#define NE 800000
#define FIN 500
#define HIDN 64
#define NH 4
#define HCD 16
#define NC 8
// kv row (padded pow2-ish): 64 bf16 Kf*dinv (128 B) + 32 bf16 V (64 B) + 64 pad = 256 B
#define KVROW 256
#define CSTF 1e-5f
#define SCAN_NB 196   // ceil(50000/256)
#define XBLKS 3125    // 50000/16 rows per block

typedef float f32x2 __attribute__((ext_vector_type(2)));
typedef __attribute__((ext_vector_type(8))) short bf16x8;
typedef __attribute__((ext_vector_type(4))) float f32x4;

// bf16 helpers (storage-only; math fp32)
__device__ inline float bf_lo(unsigned u) {
    union { unsigned i; float f; } v; v.i = u << 16; return v.f;
}
__device__ inline f32x2 bfpair(unsigned u) {
    union { unsigned i; float f; } lo, hi;
    lo.i = u << 16; hi.i = u & 0xffff0000u;
    f32x2 r; r.x = lo.f; r.y = hi.f; return r;
}
__device__ inline unsigned short f2bf(float f) {
    union { float f; unsigned i; } v; v.f = f;
    unsigned r = v.i + 0x7fffu + ((v.i >> 16) & 1u);   // RNE
    return (unsigned short)(r >> 16);
}
__device__ inline unsigned pack2bf(float a, float b) {
    __hip_bfloat162 h = __float22bfloat162_rn(make_float2(a, b));
    unsigned r; __builtin_memcpy(&r, &h, 4); return r;
}

// ---------------- degree count + Wt transpose (independent, merged) ---------

__global__ void k_deg_wt(const int* __restrict__ col, int* __restrict__ deg,
                         const float* __restrict__ Wi, unsigned short* __restrict__ Wt) {
    int e = blockIdx.x * blockDim.x + threadIdx.x;
    if (e < NE) atomicAdd(&deg[col[e]], 1);
    if (e < 64 * 512) {
        int c = e >> 9;
        int k = e & 511;
        Wt[e] = (k < FIN) ? f2bf(Wi[(size_t)k * 64 + c]) : (unsigned short)0;
    }
}

// ---------------- block sums + deginv + cursor + tMK zero (merged) ----------

__global__ void k_bsum(const int* __restrict__ deg, int* __restrict__ bsum,
                       float* __restrict__ dinv, int* __restrict__ cursor,
                       float* __restrict__ tMK) {
    __shared__ int red[256];
    int b = blockIdx.x, t = threadIdx.x;
    int i = b * 256 + t;
    int d = (i < NN) ? deg[i] : 0;
    if (i < NN) {
        dinv[i] = d > 0 ? 1.0f / (float)d : 0.0f;
        cursor[i] = 0;
    }
    if (b == 0)
        for (int j = t; j < 576; j += 256) tMK[j] = 0.f;
    red[t] = d;
    __syncthreads();
    for (int s = 128; s > 0; s >>= 1) {
        if (t < s) red[t] += red[t + s];
        __syncthreads();
    }
    if (t == 0) bsum[b] = red[0];
}

__global__ void k_bscan(const int* __restrict__ bsum, int* __restrict__ bex) {
    __shared__ int s[256];
    int t = threadIdx.x;
    int own = (t < SCAN_NB) ? bsum[t] : 0;
    s[t] = own;
    __syncthreads();
    for (int d = 1; d < 256; d <<= 1) {
        int v = (t >= d) ? s[t - d] : 0;
        __syncthreads();
        s[t] += v;
        __syncthreads();
    }
    if (t < SCAN_NB) bex[t] = s[t] - own;   // exclusive
}

__global__ void k_expand(const int* __restrict__ deg, const int* __restrict__ bex,
                         int* __restrict__ offs) {
    __shared__ int s[256];
    int b = blockIdx.x, t = threadIdx.x;
    int i = b * 256 + t;
    int v = (i < NN) ? deg[i] : 0;
    s[t] = v;
    __syncthreads();
    for (int d = 1; d < 256; d <<= 1) {
        int a = (t >= d) ? s[t - d] : 0;
        __syncthreads();
        s[t] += a;
        __syncthreads();
    }
    int excl = s[t] - v + bex[b];
    if (i < NN) offs[i] = excl;
    if (i == NN - 1) offs[NN] = excl + v;
}

__global__ void k_scatter(const int* __restrict__ row, const int* __restrict__ col,
                          const int* __restrict__ offs, int* __restrict__ cursor,
                          int* __restrict__ csr_src) {
    int e = blockIdx.x * blockDim.x + threadIdx.x;
    if (e < NE) {
        int c = col[e];
        int pos = offs[c] + atomicAdd(&cursor[c], 1);
        csr_src[pos] = row[e];
    }
}

// ---------------- x = relu(nf @ Wi + bi), bf16 MFMA -------------------------
// 3125 blocks x 4 waves: block owns 16 rows, wave owns K-quarter (128).

__global__ __launch_bounds__(256) void k_xgemm(const float* __restrict__ nf,
                                               const unsigned short* __restrict__ Wt,
                                               const float* __restrict__ bi,
                                               float* __restrict__ x) {
    __shared__ float red[4][16][68];   // [wave][row][col+pad] = 17408 B
    int t = threadIdx.x;
    int lane = t & 63;
    int w = t >> 6;                    // K-quarter
    int quad = lane >> 4;
    int l15 = lane & 15;
    int n0 = blockIdx.x * 16;
    const float* rp = nf + (size_t)(n0 + l15) * FIN;
    int kbase = w * 128;

    float4 a0[4], a1[4];
#pragma unroll
    for (int ks = 0; ks < 4; ks++) {
        int kk = kbase + ks * 32 + quad * 8;
        int c0 = kk > 496 ? 496 : kk;            // clamp; k>=500 hits Wt zeros
        int c1 = kk + 4 > 496 ? 496 : kk + 4;
        a0[ks] = *(const float4*)(rp + c0);
        a1[ks] = *(const float4*)(rp + c1);
    }

    f32x4 acc[4];
#pragma unroll
    for (int ct = 0; ct < 4; ct++) acc[ct] = (f32x4){0.f, 0.f, 0.f, 0.f};

#pragma unroll
    for (int ks = 0; ks < 4; ks++) {
        union { unsigned u[4]; bf16x8 v; } A;
        A.u[0] = pack2bf(a0[ks].x, a0[ks].y);
        A.u[1] = pack2bf(a0[ks].z, a0[ks].w);
        A.u[2] = pack2bf(a1[ks].x, a1[ks].y);
        A.u[3] = pack2bf(a1[ks].z, a1[ks].w);
        int kk = kbase + ks * 32 + quad * 8;
#pragma unroll
        for (int ct = 0; ct < 4; ct++) {
            bf16x8 b = *(const bf16x8*)&Wt[(size_t)(ct * 16 + l15) * 512 + kk];
            acc[ct] = __builtin_amdgcn_mfma_f32_16x16x32_bf16(A.v, b, acc[ct], 0, 0, 0);
        }
    }

#pragma unroll
    for (int ct = 0; ct < 4; ct++)
#pragma unroll
        for (int r = 0; r < 4; r++)
            red[w][quad * 4 + r][ct * 16 + l15] = acc[ct][r];
    __syncthreads();

    int ocol = t & 63;
    int orow0 = t >> 6;
    float bv = bi[ocol];
#pragma unroll
    for (int i = 0; i < 4; i++) {
        int orow = i * 4 + orow0;
        float s = red[0][orow][ocol] + red[1][orow][ocol]
                + red[2][orow][ocol] + red[3][orow][ocol];
        x[(size_t)(n0 + orow) * 64 + ocol] = fmaxf(s + bv, 0.f);
    }
}

// ---------------- QKV + kv row + teleport sums ----------------

__global__ __launch_bounds__(256) void k_qkv(const float* __restrict__ x,
    const float* __restrict__ Wq, const float* __restrict__ bq,
    const float* __restrict__ Wk, const float* __restrict__ bk,
    const float* __restrict__ Wv, const float* __restrict__ bv,
    const float* __restrict__ hopwise, const float* __restrict__ dinv,
    float* __restrict__ Qg, float* __restrict__ hid,
    unsigned char* __restrict__ kv0, float* __restrict__ tMK) {
    __shared__ float wq_s[64 * 64], wk_s[64 * 64], wv_s[64 * 32];
    __shared__ float bq_s[64], bk_s[64], bv_s[32];
    __shared__ float xs[4][8][64];
    __shared__ float tacc[576];
    int t = threadIdx.x;
    for (int i = t; i < 4096; i += 256) { wq_s[i] = Wq[i]; wk_s[i] = Wk[i]; }
    for (int i = t; i < 2048; i += 256) wv_s[i] = Wv[i];
    if (t < 64) { bq_s[t] = bq[t]; bk_s[t] = bk[t]; }
    if (t >= 64 && t < 96) bv_s[t - 64] = bv[t - 64];
    for (int i = t; i < 576; i += 256) tacc[i] = 0.f;
    __syncthreads();
    int lane = t & 63;
    int w = t >> 6;
    int h = lane >> 4;
    int vcol = lane & 31;
    float hw0 = hopwise[0];
    float tkp = 0.f;
    float tmp_[8];
#pragma unroll
    for (int j = 0; j < 8; j++) tmp_[j] = 0.f;
    int tiles = (NN + 31) >> 5;
    for (int tile = blockIdx.x; tile < tiles; tile += gridDim.x) {
        int n0 = tile * 32 + w * 8;
        __syncthreads();
#pragma unroll
        for (int u = 0; u < 8; u++) {
            int n = n0 + u;
            xs[w][u][lane] = (n < NN) ? x[(size_t)n * 64 + lane] : 0.f;
        }
        __syncthreads();
        float aq[8], ak[8], av[8];
#pragma unroll
        for (int u = 0; u < 8; u++) { aq[u] = 0.f; ak[u] = 0.f; av[u] = 0.f; }
        for (int f = 0; f < 64; f++) {
            float wqv = wq_s[f * 64 + lane];
            float wkv = wk_s[f * 64 + lane];
            float wvv = wv_s[f * 32 + vcol];
#pragma unroll
            for (int u = 0; u < 8; u++) {
                float xf = xs[w][u][f];
                aq[u] = fmaf(xf, wqv, aq[u]);
                ak[u] = fmaf(xf, wkv, ak[u]);
                av[u] = fmaf(xf, wvv, av[u]);
            }
        }
#pragma unroll
        for (int u = 0; u < 8; u++) {
            int n = n0 + u;
            float q = aq[u] + bq_s[lane];
            float k = ak[u] + bk_s[lane];
            float v = av[u] + bv_s[vcol];
            float Qv = q > 0.f ? 1.f + q : expf(q);   // 1 + elu
            float Kv = k > 0.f ? 1.f + k : expf(k);
            if (n < NN) {
                Qg[(size_t)n * 64 + lane] = Qv;
                float vj[8];
#pragma unroll
                for (int j = 0; j < 8; j++) vj[j] = __shfl(v, h * 8 + j, 64);
                tkp += Kv;
#pragma unroll
                for (int j = 0; j < 8; j++) tmp_[j] += Kv * vj[j];
                float dv = dinv[n];
                unsigned short* kvrow = (unsigned short*)(kv0 + (size_t)n * KVROW);
                kvrow[lane] = f2bf(Kv * dv);
                if (lane < 32) kvrow[64 + lane] = f2bf(v);
                if (lane < 32) hid[(size_t)n * 32 + lane] = v * hw0;
            }
        }
    }
#pragma unroll
    for (int j = 0; j < 8; j++) atomicAdd(&tacc[lane * 8 + j], tmp_[j]);
    atomicAdd(&tacc[512 + lane], tkp);
    __syncthreads();
    for (int i = t; i < 576; i += 256) atomicAdd(&tMK[i], tacc[i]);
}

// ---------------- hop 0: pair-gather kv0, outer-product, write Marr/Karr ----
// 32 lanes per edge, 2 edges per wave-instruction. Lane m=(l&31):
// h=m>>3, i0=(m&7)*2, i1=i0+1. Per pair p: K = uint @ m*4 (2 bf16),
// V = uint4 broadcast @ 128+h*16. Accumulate M1[h][i0/i1][j0..7].

__global__ __launch_bounds__(256) void k_hop0(const unsigned char* __restrict__ kv0,
    const int* __restrict__ offs, const int* __restrict__ csr_src,
    const float* __restrict__ dinv, const float* __restrict__ Qg,
    const float* __restrict__ hopwise, const float* __restrict__ headwise,
    unsigned char* __restrict__ Marr, unsigned char* __restrict__ Karr,
    float* __restrict__ hid) {
    int t = threadIdx.x;
    int lane = t & 63;
    int n = __builtin_amdgcn_readfirstlane((blockIdx.x * 256 + t) >> 6);
    if (n >= NN) return;
    int m = lane & 31;
    int half = lane >> 5;
    int h = m >> 3;
    float e0 = expf(headwise[0]);
    float e1 = expf(headwise[2]);
    float e2 = expf(headwise[4]);
    float e3 = expf(headwise[6]);
    float esum = e0 + e1 + e2 + e3;
    float eh = (h == 0) ? e0 : ((h == 1) ? e1 : ((h == 2) ? e2 : e3));
    float gam = hopwise[1] * eh / esum;

    int o0 = offs[n], o1 = offs[n + 1];
    f32x2 qv2 = *(const f32x2*)(Qg + (size_t)n * 64 + m * 2);   // (q_i0, q_i1)
    f32x2 acc0[4], acc1[4], kacc2;
#pragma unroll
    for (int p = 0; p < 4; p++) { acc0[p] = (f32x2){0.f, 0.f}; acc1[p] = (f32x2){0.f, 0.f}; }
    kacc2 = (f32x2){0.f, 0.f};

    int idx[8];
#pragma unroll
    for (int q = 0; q < 8; q++) idx[q] = (o0 + q < o1) ? csr_src[o0 + q] : NN;
    for (int e = o0; e < o1; e += 8) {
        unsigned kw[4]; uint4 vv[4];
#pragma unroll
        for (int p = 0; p < 4; p++) {
            int sel = half ? idx[2 * p + 1] : idx[2 * p];
            const unsigned char* r = kv0 + (size_t)sel * KVROW;
            kw[p] = *(const unsigned*)(r + m * 4);
            vv[p] = *(const uint4*)(r + 128 + h * 16);
        }
        int e2n = e + 8;
#pragma unroll
        for (int q = 0; q < 8; q++) idx[q] = (e2n + q < o1) ? csr_src[e2n + q] : NN;
#pragma unroll
        for (int p = 0; p < 4; p++) {
            f32x2 kf = bfpair(kw[p]);          // (Kf*dinv)[h][i0], [i1]
            f32x2 v01 = bfpair(vv[p].x);
            f32x2 v23 = bfpair(vv[p].y);
            f32x2 v45 = bfpair(vv[p].z);
            f32x2 v67 = bfpair(vv[p].w);
            f32x2 k0; k0.x = kf.x; k0.y = kf.x;
            f32x2 k1; k1.x = kf.y; k1.y = kf.y;
            acc0[0] += k0 * v01; acc0[1] += k0 * v23;
            acc0[2] += k0 * v45; acc0[3] += k0 * v67;
            acc1[0] += k1 * v01; acc1[1] += k1 * v23;
            acc1[2] += k1 * v45; acc1[3] += k1 * v67;
            kacc2 += kf;
        }
    }
    // cross-half reduce: full M1/K1 on all lanes
#pragma unroll
    for (int p = 0; p < 4; p++) {
        acc0[p].x += __shfl_xor(acc0[p].x, 32, 64);
        acc0[p].y += __shfl_xor(acc0[p].y, 32, 64);
        acc1[p].x += __shfl_xor(acc1[p].x, 32, 64);
        acc1[p].y += __shfl_xor(acc1[p].y, 32, 64);
    }
    kacc2.x += __shfl_xor(kacc2.x, 32, 64);
    kacc2.y += __shfl_xor(kacc2.y, 32, 64);

    // write Marr (M1*dinv*16 fp8, 16B/lane) + Karr (K1*dinv*8 fp8, 2B/lane)
    float dv = dinv[n];
    float s8 = dv * 8.f;
    float s16 = dv * 16.f;
    if (half == 0) {
        uint4 pk;
        unsigned u;
        u = __builtin_amdgcn_cvt_pk_fp8_f32(acc0[0].x * s16, acc0[0].y * s16, 0, false);
        u = __builtin_amdgcn_cvt_pk_fp8_f32(acc0[1].x * s16, acc0[1].y * s16, u, true);
        pk.x = u;
        u = __builtin_amdgcn_cvt_pk_fp8_f32(acc0[2].x * s16, acc0[2].y * s16, 0, false);
        u = __builtin_amdgcn_cvt_pk_fp8_f32(acc0[3].x * s16, acc0[3].y * s16, u, true);
        pk.y = u;
        u = __builtin_amdgcn_cvt_pk_fp8_f32(acc1[0].x * s16, acc1[0].y * s16, 0, false);
        u = __builtin_amdgcn_cvt_pk_fp8_f32(acc1[1].x * s16, acc1[1].y * s16, u, true);
        pk.z = u;
        u = __builtin_amdgcn_cvt_pk_fp8_f32(acc1[2].x * s16, acc1[2].y * s16, 0, false);
        u = __builtin_amdgcn_cvt_pk_fp8_f32(acc1[3].x * s16, acc1[3].y * s16, u, true);
        pk.w = u;
        *(uint4*)(Marr + (size_t)n * 512 + m * 16) = pk;
        unsigned kb = __builtin_amdgcn_cvt_pk_fp8_f32(kacc2.x * s8, kacc2.y * s8, 0, false);
        *(unsigned short*)(Karr + (size_t)n * 64 + m * 2) = (unsigned short)(kb & 0xffff);
    }

    // attend (true-scale): hh[j] = sum_i q_i * M1[h][i][j]
    f32x2 qx; qx.x = qv2.x; qx.y = qv2.x;
    f32x2 qy; qy.x = qv2.y; qy.y = qv2.y;
    f32x2 hh[4];
#pragma unroll
    for (int p = 0; p < 4; p++) hh[p] = qx * acc0[p] + qy * acc1[p];
    float cc = qv2.x * kacc2.x + qv2.y * kacc2.y;
#pragma unroll
    for (int s = 1; s < 8; s <<= 1) {
#pragma unroll
        for (int p = 0; p < 4; p++) {
            hh[p].x += __shfl_xor(hh[p].x, s, 64);
            hh[p].y += __shfl_xor(hh[p].y, s, 64);
        }
        cc += __shfl_xor(cc, s, 64);
    }
    if (half == 0) {
        int j = m & 7;
        float val = (j < 4) ? ((j < 2) ? ((j == 0) ? hh[0].x : hh[0].y)
                                       : ((j == 2) ? hh[1].x : hh[1].y))
                            : ((j < 6) ? ((j == 4) ? hh[2].x : hh[2].y)
                                       : ((j == 6) ? hh[3].x : hh[3].y));
        hid[(size_t)n * 32 + m] += gam * val / (cc + CSTF);
    }
}

// ---------------- hop 1: pair-gather Marr/Karr (fp8), attend ----------------

__global__ __launch_bounds__(256) void k_prop1(const unsigned char* __restrict__ Marr,
    const unsigned char* __restrict__ Karr,
    const int* __restrict__ offs, const int* __restrict__ csr_src,
    const float* __restrict__ Qg, const float* __restrict__ hopwise,
    const float* __restrict__ headwise, float* __restrict__ hid) {
    int t = threadIdx.x;
    int lane = t & 63;
    int n = __builtin_amdgcn_readfirstlane((blockIdx.x * 256 + t) >> 6);
    if (n >= NN) return;
    int m = lane & 31;
    int half = lane >> 5;
    int h = m >> 3;
    float e0 = expf(headwise[1]);
    float e1 = expf(headwise[3]);
    float e2 = expf(headwise[5]);
    float e3 = expf(headwise[7]);
    float esum = e0 + e1 + e2 + e3;
    float eh = (h == 0) ? e0 : ((h == 1) ? e1 : ((h == 2) ? e2 : e3));
    float gam = hopwise[2] * eh / esum * 0.0625f;   // 1/16 M-scale folded in

    int o0 = offs[n], o1 = offs[n + 1];
    f32x2 qv2 = *(const f32x2*)(Qg + (size_t)n * 64 + m * 2);   // (q_i0, q_i1)
    f32x2 acc0[4], acc1[4], kacc2;
#pragma unroll
    for (int p = 0; p < 4; p++) { acc0[p] = (f32x2){0.f, 0.f}; acc1[p] = (f32x2){0.f, 0.f}; }
    kacc2 = (f32x2){0.f, 0.f};

    int idx[8];
#pragma unroll
    for (int q = 0; q < 8; q++) idx[q] = (o0 + q < o1) ? csr_src[o0 + q] : NN;
    for (int e = o0; e < o1; e += 8) {
        uint4 mv[4]; unsigned kb[4];
#pragma unroll
        for (int p = 0; p < 4; p++) {
            int sel = half ? idx[2 * p + 1] : idx[2 * p];
            mv[p] = *(const uint4*)(Marr + (size_t)sel * 512 + m * 16);
            kb[p] = *(const unsigned short*)(Karr + (size_t)sel * 64 + m * 2);
        }
        int e2n = e + 8;
#pragma unroll
        for (int q = 0; q < 8; q++) idx[q] = (e2n + q < o1) ? csr_src[e2n + q] : NN;
#pragma unroll
        for (int p = 0; p < 4; p++) {
            acc0[0] += __builtin_amdgcn_cvt_pk_f32_fp8(mv[p].x, false);
            acc0[1] += __builtin_amdgcn_cvt_pk_f32_fp8(mv[p].x, true);
            acc0[2] += __builtin_amdgcn_cvt_pk_f32_fp8(mv[p].y, false);
            acc0[3] += __builtin_amdgcn_cvt_pk_f32_fp8(mv[p].y, true);
            acc1[0] += __builtin_amdgcn_cvt_pk_f32_fp8(mv[p].z, false);
            acc1[1] += __builtin_amdgcn_cvt_pk_f32_fp8(mv[p].z, true);
            acc1[2] += __builtin_amdgcn_cvt_pk_f32_fp8(mv[p].w, false);
            acc1[3] += __builtin_amdgcn_cvt_pk_f32_fp8(mv[p].w, true);
            kacc2 += __builtin_amdgcn_cvt_pk_f32_fp8(kb[p], false);
        }
    }
    // attend partials; stride-32 step completes the edge sum across halves
    f32x2 qx; qx.x = qv2.x; qx.y = qv2.x;
    f32x2 qy; qy.x = qv2.y; qy.y = qv2.y;
    f32x2 hh[4];
#pragma unroll
    for (int p = 0; p < 4; p++) hh[p] = qx * acc0[p] + qy * acc1[p];
    float cc = (qv2.x * kacc2.x + qv2.y * kacc2.y) * 0.125f;   // undo K x8
#pragma unroll
    for (int s = 1; s < 8; s <<= 1) {
#pragma unroll
        for (int p = 0; p < 4; p++) {
            hh[p].x += __shfl_xor(hh[p].x, s, 64);
            hh[p].y += __shfl_xor(hh[p].y, s, 64);
        }
        cc += __shfl_xor(cc, s, 64);
    }
#pragma unroll
    for (int p = 0; p < 4; p++) {
        hh[p].x += __shfl_xor(hh[p].x, 32, 64);
        hh[p].y += __shfl_xor(hh[p].y, 32, 64);
    }
    cc += __shfl_xor(cc, 32, 64);
    if (half == 0) {
        int j = m & 7;
        float val = (j < 4) ? ((j < 2) ? ((j == 0) ? hh[0].x : hh[0].y)
                                       : ((j == 2) ? hh[1].x : hh[1].y))
                            : ((j < 6) ? ((j == 4) ? hh[2].x : hh[2].y)
                                       : ((j == 6) ? hh[3].x : hh[3].y));
        hid[(size_t)n * 32 + m] += gam * val / (cc + CSTF);
    }
}

// ---------------- final: out = hidden @ Wo + bo + teleport * teleportH ------

__global__ __launch_bounds__(256) void k_final(const float* __restrict__ hid,
    const float* __restrict__ Qg, const float* __restrict__ Wo,
    const float* __restrict__ bo, const float* __restrict__ tMK,
    const float* __restrict__ teleport, float* __restrict__ out) {
    __shared__ float tm[512];
    __shared__ float tk[64];
    __shared__ float wo[256];
    __shared__ float bos[8];
    int t = threadIdx.x;
    const float invN = 1.0f / (float)NN;
    for (int i = t; i < 512; i += 256) tm[i] = tMK[i] * invN;
    if (t < 64) tk[t] = tMK[512 + t] * invN;
    wo[t] = Wo[t & 255];
    if (t < 8) bos[t] = bo[t];
    __syncthreads();
    float tp = teleport[0];
    int lane = t & 63;
    int sub = lane & 7;
    int g = lane >> 3;
    int wid = (blockIdx.x * 256 + t) >> 6;
    int nwaves = gridDim.x * 4;
    for (int nb = wid * 8; nb < NN; nb += nwaves * 8) {
        int n = nb + g;
        if (n < NN) {
            const float* hrow = hid + (size_t)n * 32;
            const float* qrow = Qg + (size_t)n * 64;
            float o = bos[sub];
#pragma unroll
            for (int m = 0; m < 32; m++) o = fmaf(hrow[m], wo[m * 8 + sub], o);
            float th = 0.f;
#pragma unroll
            for (int h2 = 0; h2 < 4; h2++) {
                float num = 0.f, den = 0.f;
#pragma unroll
                for (int i = 0; i < 16; i++) {
                    float q = qrow[h2 * 16 + i];
                    num = fmaf(q, tm[h2 * 128 + i * 8 + sub], num);
                    den = fmaf(q, tk[h2 * 16 + i], den);
                }
                th += num / (den + CSTF);
            }
            out[(size_t)n * 8 + sub] = o + tp * th;
        }
    }
}

// ---------------- launch ----------------

extern "C" void kernel_launch(void* const* d_in, const int* in_sizes, int n_in,
                              void* d_out, int out_size, void* d_ws, size_t ws_size,
                              hipStream_t stream) {
    const float* nf = (const float*)d_in[0];
    const int* ei = (const int*)d_in[1];
    const float* Wi = (const float*)d_in[2];
    const float* bi = (const float*)d_in[3];
    const float* Wq = (const float*)d_in[4];
    const float* bq = (const float*)d_in[5];
    const float* Wk = (const float*)d_in[6];
    const float* bk = (const float*)d_in[7];
    const float* Wv = (const float*)d_in[8];
    const float* bv = (const float*)d_in[9];
    const float* Wo = (const float*)d_in[10];
    const float* bo = (const float*)d_in[11];
    const float* hopwise = (const float*)d_in[12];
    const float* headwise = (const float*)d_in[13];
    const float* teleport = (const float*)d_in[14];
    float* out = (float*)d_out;

    char* base = (char*)d_ws;
    size_t off = 0;
    auto alloc = [&](size_t bytes) -> void* {
        void* p = base + off;
        off = (off + bytes + 255) & ~(size_t)255;
        return p;
    };
    int* deg = (int*)alloc(NN * 4);
    int* cursor = (int*)alloc(NN * 4);
    int* offs = (int*)alloc((NN + 1) * 4);
    int* bsum = (int*)alloc(256 * 4);
    int* bex = (int*)alloc(256 * 4);
    float* dinv = (float*)alloc(NN * 4);
    int* csr_src = (int*)alloc((size_t)NE * 4);
    unsigned short* Wt = (unsigned short*)alloc(64 * 512 * 2);
    float* xbuf = (float*)alloc((size_t)NN * 64 * 4);
    float* Qg = (float*)alloc((size_t)NN * 64 * 4);
    float* hid = (float*)alloc((size_t)NN * 32 * 4);
    unsigned char* kv0 = (unsigned char*)alloc((size_t)(NN + 1) * KVROW);  // +1 zero row
    unsigned char* Marr = (unsigned char*)alloc((size_t)(NN + 1) * 512);  // +1 zero row
    unsigned char* Karr = (unsigned char*)alloc((size_t)(NN + 1) * 64);   // +1 zero row
    float* tMK = (float*)alloc(576 * 4);

    const int* rowp = ei;
    const int* colp = ei + NE;

    hipMemsetAsync(deg, 0, NN * 4, stream);
    hipMemsetAsync(kv0 + (size_t)NN * KVROW, 0, KVROW, stream);
    hipMemsetAsync(Marr + (size_t)NN * 512, 0, 512, stream);
    hipMemsetAsync(Karr + (size_t)NN * 64, 0, 64, stream);

    k_deg_wt<<<(NE + 255) / 256, 256, 0, stream>>>(colp, deg, Wi, Wt);
    k_bsum<<<SCAN_NB, 256, 0, stream>>>(deg, bsum, dinv, cursor, tMK);
    k_bscan<<<1, 256, 0, stream>>>(bsum, bex);
    k_expand<<<SCAN_NB, 256, 0, stream>>>(deg, bex, offs);
    k_scatter<<<(NE + 255) / 256, 256, 0, stream>>>(rowp, colp, offs, cursor, csr_src);
    k_xgemm<<<XBLKS, 256, 0, stream>>>(nf, Wt, bi, xbuf);
    k_qkv<<<768, 256, 0, stream>>>(xbuf, Wq, bq, Wk, bk, Wv, bv, hopwise, dinv,
                                   Qg, hid, kv0, tMK);
    k_hop0<<<(NN * 64 + 255) / 256, 256, 0, stream>>>(kv0, offs, csr_src, dinv, Qg,
                                                      hopwise, headwise, Marr, Karr, hid);
    k_prop1<<<(NN * 64 + 255) / 256, 256, 0, stream>>>(Marr, Karr, offs, csr_src, Qg,
                                                       hopwise, headwise, hid);
    k_final<<<1563, 256, 0, stream>>>(hid, Qg, Wo, bo, tMK, teleport, out);
}

// Round 8
// 445.987 us; speedup vs baseline: 1.1664x; 1.1664x over previous
//
#include <hip/hip_runtime.h>
#include <hip/hip_bf16.h>
#include <stdint.h>
#include <stddef.h>

#define NN 50000
#define NE 800000
#define FIN 500
#define HIDN 64
#define NH 4
#define HCD 16
#define NC 8
// kv row: 64 bf16 Kf*dinv (128 B) + 32 bf16 V (64 B) = 192 B
#define KVROW 192
// S1 row: 64 fp8 K1*dinv*8 (64 B) + 512 fp8 M1*dinv*16 (512 B) = 576 B
#define SROW 576
#define CSTF 1e-5f
#define SCAN_NB 196   // ceil(50000/256)
#define XBLKS 3125    // 50000/16 rows per block

typedef float f32x2 __attribute__((ext_vector_type(2)));
typedef __attribute__((ext_vector_type(8))) short bf16x8;
typedef __attribute__((ext_vector_type(4))) float f32x4;

// bf16 helpers (storage-only; math fp32)
__device__ inline float bf_lo(unsigned u) {
    union { unsigned i; float f; } v; v.i = u << 16; return v.f;
}
__device__ inline f32x2 bfpair(unsigned u) {
    union { unsigned i; float f; } lo, hi;
    lo.i = u << 16; hi.i = u & 0xffff0000u;
    f32x2 r; r.x = lo.f; r.y = hi.f; return r;
}
__device__ inline unsigned short f2bf(float f) {
    union { float f; unsigned i; } v; v.f = f;
    unsigned r = v.i + 0x7fffu + ((v.i >> 16) & 1u);   // RNE
    return (unsigned short)(r >> 16);
}
__device__ inline unsigned pack2bf(float a, float b) {
    __hip_bfloat162 h = __float22bfloat162_rn(make_float2(a, b));
    unsigned r; __builtin_memcpy(&r, &h, 4); return r;
}

// ---------------- degree count + Wt transpose (independent, merged) ---------

__global__ void k_deg_wt(const int* __restrict__ col, int* __restrict__ deg,
                         const float* __restrict__ Wi, unsigned short* __restrict__ Wt) {
    int e = blockIdx.x * blockDim.x + threadIdx.x;
    if (e < NE) atomicAdd(&deg[col[e]], 1);
    if (e < 64 * 512) {
        int c = e >> 9;
        int k = e & 511;
        Wt[e] = (k < FIN) ? f2bf(Wi[(size_t)k * 64 + c]) : (unsigned short)0;
    }
}

// ---------------- block sums + deginv + cursor + tMK zero (merged) ----------

__global__ void k_bsum(const int* __restrict__ deg, int* __restrict__ bsum,
                       float* __restrict__ dinv, int* __restrict__ cursor,
                       float* __restrict__ tMK) {
    __shared__ int red[256];
    int b = blockIdx.x, t = threadIdx.x;
    int i = b * 256 + t;
    int d = (i < NN) ? deg[i] : 0;
    if (i < NN) {
        dinv[i] = d > 0 ? 1.0f / (float)d : 0.0f;
        cursor[i] = 0;
    }
    if (b == 0)
        for (int j = t; j < 576; j += 256) tMK[j] = 0.f;
    red[t] = d;
    __syncthreads();
    for (int s = 128; s > 0; s >>= 1) {
        if (t < s) red[t] += red[t + s];
        __syncthreads();
    }
    if (t == 0) bsum[b] = red[0];
}

__global__ void k_bscan(const int* __restrict__ bsum, int* __restrict__ bex) {
    __shared__ int s[256];
    int t = threadIdx.x;
    int own = (t < SCAN_NB) ? bsum[t] : 0;
    s[t] = own;
    __syncthreads();
    for (int d = 1; d < 256; d <<= 1) {
        int v = (t >= d) ? s[t - d] : 0;
        __syncthreads();
        s[t] += v;
        __syncthreads();
    }
    if (t < SCAN_NB) bex[t] = s[t] - own;   // exclusive
}

__global__ void k_expand(const int* __restrict__ deg, const int* __restrict__ bex,
                         int* __restrict__ offs) {
    __shared__ int s[256];
    int b = blockIdx.x, t = threadIdx.x;
    int i = b * 256 + t;
    int v = (i < NN) ? deg[i] : 0;
    s[t] = v;
    __syncthreads();
    for (int d = 1; d < 256; d <<= 1) {
        int a = (t >= d) ? s[t - d] : 0;
        __syncthreads();
        s[t] += a;
        __syncthreads();
    }
    int excl = s[t] - v + bex[b];
    if (i < NN) offs[i] = excl;
    if (i == NN - 1) offs[NN] = excl + v;
}

__global__ void k_scatter(const int* __restrict__ row, const int* __restrict__ col,
                          const int* __restrict__ offs, int* __restrict__ cursor,
                          int* __restrict__ csr_src) {
    int e = blockIdx.x * blockDim.x + threadIdx.x;
    if (e < NE) {
        int c = col[e];
        int pos = offs[c] + atomicAdd(&cursor[c], 1);
        csr_src[pos] = row[e];
    }
}

// ---------------- x = relu(nf @ Wi + bi), bf16 MFMA -------------------------
// Many-block one-phase (R5) + CONTIGUOUS staging (R8): wave w loads its 4
// rows as full-line 16B/lane streams into a bank-even fp32 LDS tile
// (stride 516), one barrier, then R5's exact fragment math (wave=K-quarter,
// clamp tail onto Wt zero pad). A-tile LDS is reused for the output reduce.

__global__ __launch_bounds__(256) void k_xgemm(const float* __restrict__ nf,
                                               const unsigned short* __restrict__ Wt,
                                               const float* __restrict__ bi,
                                               float* __restrict__ x) {
    __shared__ __align__(16) float atile[16 * 516];   // 33 KB; reused for reduce
    int t = threadIdx.x;
    int lane = t & 63;
    int w = t >> 6;
    int quad = lane >> 4;
    int l15 = lane & 15;
    int n0 = blockIdx.x * 16;

    // ---- stage: wave w loads rows w*4 .. w*4+3, contiguous 16 B/lane
#pragma unroll
    for (int i = 0; i < 4; i++) {
        int r = w * 4 + i;
        const float* rp = nf + (size_t)(n0 + r) * FIN;
        float4 v0 = *(const float4*)(rp + 4 * lane);        // floats 0..255
        int c1 = 256 + 4 * lane;                            // floats 256..511
        int c1c = c1 > 496 ? 496 : c1;   // lanes 61-63 dup; land in cols>=500
        float4 v1 = *(const float4*)(rp + c1c);
        *(float4*)&atile[r * 516 + 4 * lane] = v0;
        *(float4*)&atile[r * 516 + c1] = v1;
    }
    __syncthreads();

    // ---- compute: wave w owns K-quarter kbase = w*128 (R5 fragment math)
    int kbase = w * 128;
    f32x4 acc[4];
#pragma unroll
    for (int ct = 0; ct < 4; ct++) acc[ct] = (f32x4){0.f, 0.f, 0.f, 0.f};

#pragma unroll
    for (int ks = 0; ks < 4; ks++) {
        int kk = kbase + ks * 32 + quad * 8;                // <= 504
        f32x4 fa = *(const f32x4*)&atile[l15 * 516 + kk];
        f32x4 fb = *(const f32x4*)&atile[l15 * 516 + kk + 4];
        union { unsigned u[4]; bf16x8 v; } A;
        A.u[0] = pack2bf(fa.x, fa.y); A.u[1] = pack2bf(fa.z, fa.w);
        A.u[2] = pack2bf(fb.x, fb.y); A.u[3] = pack2bf(fb.z, fb.w);
#pragma unroll
        for (int ct = 0; ct < 4; ct++) {
            bf16x8 b = *(const bf16x8*)&Wt[(size_t)(ct * 16 + l15) * 512 + kk];
            acc[ct] = __builtin_amdgcn_mfma_f32_16x16x32_bf16(A.v, b, acc[ct], 0, 0, 0);
        }
    }
    __syncthreads();   // all A-reads done; reuse atile as reduce buffer

    // stash partials: red[w][row][col] with stride 68 (bank-friendly)
    float* red = atile;
#pragma unroll
    for (int ct = 0; ct < 4; ct++)
#pragma unroll
        for (int r = 0; r < 4; r++)
            red[(w * 16 + quad * 4 + r) * 68 + ct * 16 + l15] = acc[ct][r];
    __syncthreads();

    // reduce 4 K-quarters + bias + relu; coalesced write
    int ocol = t & 63;
    int orow0 = t >> 6;
    float bv = bi[ocol];
#pragma unroll
    for (int i = 0; i < 4; i++) {
        int orow = i * 4 + orow0;
        float s = red[(0 * 16 + orow) * 68 + ocol] + red[(1 * 16 + orow) * 68 + ocol]
                + red[(2 * 16 + orow) * 68 + ocol] + red[(3 * 16 + orow) * 68 + ocol];
        x[(size_t)(n0 + orow) * 64 + ocol] = fmaxf(s + bv, 0.f);
    }
}

// ---------------- QKV + kv row + teleport sums ----------------

__global__ __launch_bounds__(256) void k_qkv(const float* __restrict__ x,
    const float* __restrict__ Wq, const float* __restrict__ bq,
    const float* __restrict__ Wk, const float* __restrict__ bk,
    const float* __restrict__ Wv, const float* __restrict__ bv,
    const float* __restrict__ hopwise, const float* __restrict__ dinv,
    float* __restrict__ Qg, float* __restrict__ hid,
    unsigned char* __restrict__ kv0, float* __restrict__ tMK) {
    __shared__ float wq_s[64 * 64], wk_s[64 * 64], wv_s[64 * 32];
    __shared__ float bq_s[64], bk_s[64], bv_s[32];
    __shared__ float xs[4][8][64];
    __shared__ float tacc[576];
    int t = threadIdx.x;
    for (int i = t; i < 4096; i += 256) { wq_s[i] = Wq[i]; wk_s[i] = Wk[i]; }
    for (int i = t; i < 2048; i += 256) wv_s[i] = Wv[i];
    if (t < 64) { bq_s[t] = bq[t]; bk_s[t] = bk[t]; }
    if (t >= 64 && t < 96) bv_s[t - 64] = bv[t - 64];
    for (int i = t; i < 576; i += 256) tacc[i] = 0.f;
    __syncthreads();
    int lane = t & 63;
    int w = t >> 6;
    int h = lane >> 4;
    int vcol = lane & 31;
    float hw0 = hopwise[0];
    float tkp = 0.f;
    float tmp_[8];
#pragma unroll
    for (int j = 0; j < 8; j++) tmp_[j] = 0.f;
    int tiles = (NN + 31) >> 5;
    for (int tile = blockIdx.x; tile < tiles; tile += gridDim.x) {
        int n0 = tile * 32 + w * 8;
        __syncthreads();
#pragma unroll
        for (int u = 0; u < 8; u++) {
            int n = n0 + u;
            xs[w][u][lane] = (n < NN) ? x[(size_t)n * 64 + lane] : 0.f;
        }
        __syncthreads();
        float aq[8], ak[8], av[8];
#pragma unroll
        for (int u = 0; u < 8; u++) { aq[u] = 0.f; ak[u] = 0.f; av[u] = 0.f; }
        for (int f = 0; f < 64; f++) {
            float wqv = wq_s[f * 64 + lane];
            float wkv = wk_s[f * 64 + lane];
            float wvv = wv_s[f * 32 + vcol];
#pragma unroll
            for (int u = 0; u < 8; u++) {
                float xf = xs[w][u][f];
                aq[u] = fmaf(xf, wqv, aq[u]);
                ak[u] = fmaf(xf, wkv, ak[u]);
                av[u] = fmaf(xf, wvv, av[u]);
            }
        }
#pragma unroll
        for (int u = 0; u < 8; u++) {
            int n = n0 + u;
            float q = aq[u] + bq_s[lane];
            float k = ak[u] + bk_s[lane];
            float v = av[u] + bv_s[vcol];
            float Qv = q > 0.f ? 1.f + q : expf(q);   // 1 + elu
            float Kv = k > 0.f ? 1.f + k : expf(k);
            if (n < NN) {
                Qg[(size_t)n * 64 + lane] = Qv;
                float vj[8];
#pragma unroll
                for (int j = 0; j < 8; j++) vj[j] = __shfl(v, h * 8 + j, 64);
                tkp += Kv;
#pragma unroll
                for (int j = 0; j < 8; j++) tmp_[j] += Kv * vj[j];
                float dv = dinv[n];
                unsigned short* kvrow = (unsigned short*)(kv0 + (size_t)n * KVROW);
                kvrow[lane] = f2bf(Kv * dv);
                if (lane < 32) kvrow[64 + lane] = f2bf(v);
                if (lane < 32) hid[(size_t)n * 32 + lane] = v * hw0;
            }
        }
    }
#pragma unroll
    for (int j = 0; j < 8; j++) atomicAdd(&tacc[lane * 8 + j], tmp_[j]);
    atomicAdd(&tacc[512 + lane], tkp);
    __syncthreads();
    for (int i = t; i < 576; i += 256) atomicAdd(&tMK[i], tacc[i]);
}

// ---------------- hop 0: gather Kf/V, outer-product on the fly --------------
// One wave per node; unroll-8; f32x2 packed accumulate. (R5 verbatim)

__global__ __launch_bounds__(256) void k_hop0(const unsigned char* __restrict__ kv0,
    const int* __restrict__ offs, const int* __restrict__ csr_src,
    const float* __restrict__ dinv, const float* __restrict__ Qg,
    const float* __restrict__ hopwise, const float* __restrict__ headwise,
    unsigned char* __restrict__ S1, float* __restrict__ hid) {
    int t = threadIdx.x;
    int lane = t & 63;
    int n = __builtin_amdgcn_readfirstlane((blockIdx.x * 256 + t) >> 6);
    if (n >= NN) return;
    int h = lane >> 4;
    float e0 = expf(headwise[0]);
    float e1 = expf(headwise[2]);
    float e2 = expf(headwise[4]);
    float e3 = expf(headwise[6]);
    float esum = e0 + e1 + e2 + e3;
    float eh = (h == 0) ? e0 : ((h == 1) ? e1 : ((h == 2) ? e2 : e3));
    float gam = hopwise[1] * eh / esum;

    int hoff = 128 + h * 16;
    int o0 = offs[n], o1 = offs[n + 1];
    float kacc = 0.f;
    f32x2 A0 = {0.f, 0.f}, A1 = {0.f, 0.f}, B0 = {0.f, 0.f}, B1 = {0.f, 0.f};
    int e = o0;
    for (; e + 7 < o1; e += 8) {
        float kk_[8]; uint4 vv[8];
#pragma unroll
        for (int q = 0; q < 8; q++) {
            int s = csr_src[e + q];
            const unsigned char* r = kv0 + (size_t)s * KVROW;
            kk_[q] = bf_lo(((const unsigned short*)r)[lane]);
            vv[q] = *(const uint4*)(r + hoff);
        }
#pragma unroll
        for (int q = 0; q < 8; q++) {
            float ka = kk_[q];
            f32x2 ka2; ka2.x = ka; ka2.y = ka;
            kacc += ka;
            A0 += ka2 * bfpair(vv[q].x);
            A1 += ka2 * bfpair(vv[q].y);
            B0 += ka2 * bfpair(vv[q].z);
            B1 += ka2 * bfpair(vv[q].w);
        }
    }
    for (; e < o1; e++) {
        int s = csr_src[e];
        const unsigned char* r = kv0 + (size_t)s * KVROW;
        float ka = bf_lo(((const unsigned short*)r)[lane]);
        uint4 va = *(const uint4*)(r + hoff);
        f32x2 ka2; ka2.x = ka; ka2.y = ka;
        kacc += ka;
        A0 += ka2 * bfpair(va.x);
        A1 += ka2 * bfpair(va.y);
        B0 += ka2 * bfpair(va.z);
        B1 += ka2 * bfpair(va.w);
    }
    // write S1: K fp8 (*dinv*8), M fp8 (*dinv*16); scales folded into hop-1
    {
        float dv = dinv[n];
        float s8 = dv * 8.f;
        float s16 = dv * 16.f;
        unsigned char* drow = S1 + (size_t)n * SROW;
        unsigned kb8 = __builtin_amdgcn_cvt_pk_fp8_f32(kacc * s8, 0.f, 0, false);
        drow[lane] = (unsigned char)(kb8 & 0xff);
        unsigned u0 = __builtin_amdgcn_cvt_pk_fp8_f32(A0.x * s16, A0.y * s16, 0, false);
        u0 = __builtin_amdgcn_cvt_pk_fp8_f32(A1.x * s16, A1.y * s16, u0, true);
        unsigned u1 = __builtin_amdgcn_cvt_pk_fp8_f32(B0.x * s16, B0.y * s16, 0, false);
        u1 = __builtin_amdgcn_cvt_pk_fp8_f32(B1.x * s16, B1.y * s16, u1, true);
        uint2 pv; pv.x = u0; pv.y = u1;
        *(uint2*)(drow + 64 + lane * 8) = pv;
    }
    // attend (true-scale)
    float qv = Qg[(size_t)n * 64 + lane];
    float hh[8];
    hh[0] = qv * A0.x; hh[1] = qv * A0.y; hh[2] = qv * A1.x; hh[3] = qv * A1.y;
    hh[4] = qv * B0.x; hh[5] = qv * B0.y; hh[6] = qv * B1.x; hh[7] = qv * B1.y;
    float cc = qv * kacc;
#pragma unroll
    for (int s = 1; s < 16; s <<= 1) {
#pragma unroll
        for (int j = 0; j < 8; j++) hh[j] += __shfl_xor(hh[j], s, 16);
        cc += __shfl_xor(cc, s, 16);
    }
    if ((lane & 15) < 8) {
        int j = lane & 7;
        float val = j < 4 ? (j < 2 ? (j == 0 ? hh[0] : hh[1]) : (j == 2 ? hh[2] : hh[3]))
                          : (j < 6 ? (j == 4 ? hh[4] : hh[5]) : (j == 6 ? hh[6] : hh[7]));
        size_t idx = (size_t)n * 32 + h * 8 + j;
        hid[idx] += gam * val / (cc + CSTF);
    }
}

// ---------------- hop 1: gather S1 (fp8 K + fp8 M), attend, unroll-8 --------
// (R5 verbatim)

__global__ __launch_bounds__(256) void k_prop1(const unsigned char* __restrict__ Sold,
    const int* __restrict__ offs, const int* __restrict__ csr_src,
    const float* __restrict__ Qg, const float* __restrict__ hopwise,
    const float* __restrict__ headwise, float* __restrict__ hid) {
    int t = threadIdx.x;
    int lane = t & 63;
    int n = __builtin_amdgcn_readfirstlane((blockIdx.x * 256 + t) >> 6);
    if (n >= NN) return;
    int h = lane >> 4;
    float e0 = expf(headwise[1]);
    float e1 = expf(headwise[3]);
    float e2 = expf(headwise[5]);
    float e3 = expf(headwise[7]);
    float esum = e0 + e1 + e2 + e3;
    float eh = (h == 0) ? e0 : ((h == 1) ? e1 : ((h == 2) ? e2 : e3));
    float gam = hopwise[2] * eh / esum * 0.0625f;   // 1/16 M-scale folded in

    int o0 = offs[n], o1 = offs[n + 1];
    float kacc = 0.f;
    f32x2 A0 = {0.f, 0.f}, A1 = {0.f, 0.f}, B0 = {0.f, 0.f}, B1 = {0.f, 0.f};
    int e = o0;
    for (; e + 7 < o1; e += 8) {
        unsigned kb[8]; uint2 mv[8];
#pragma unroll
        for (int q = 0; q < 8; q++) {
            int s = csr_src[e + q];
            const unsigned char* r = Sold + (size_t)s * SROW;
            kb[q] = r[lane];
            mv[q] = *(const uint2*)(r + 64 + lane * 8);
        }
#pragma unroll
        for (int q = 0; q < 8; q++) {
            f32x2 kv = __builtin_amdgcn_cvt_pk_f32_fp8(kb[q], false);
            kacc += kv.x;
            A0 += __builtin_amdgcn_cvt_pk_f32_fp8(mv[q].x, false);
            A1 += __builtin_amdgcn_cvt_pk_f32_fp8(mv[q].x, true);
            B0 += __builtin_amdgcn_cvt_pk_f32_fp8(mv[q].y, false);
            B1 += __builtin_amdgcn_cvt_pk_f32_fp8(mv[q].y, true);
        }
    }
    for (; e < o1; e++) {
        int s = csr_src[e];
        const unsigned char* r = Sold + (size_t)s * SROW;
        unsigned kb = r[lane];
        uint2 mva = *(const uint2*)(r + 64 + lane * 8);
        f32x2 kv = __builtin_amdgcn_cvt_pk_f32_fp8(kb, false);
        kacc += kv.x;
        A0 += __builtin_amdgcn_cvt_pk_f32_fp8(mva.x, false);
        A1 += __builtin_amdgcn_cvt_pk_f32_fp8(mva.x, true);
        B0 += __builtin_amdgcn_cvt_pk_f32_fp8(mva.y, false);
        B1 += __builtin_amdgcn_cvt_pk_f32_fp8(mva.y, true);
    }
    kacc *= 0.125f;   // undo K fp8 storage scale (x8)
    float qv = Qg[(size_t)n * 64 + lane];
    float hh[8];
    hh[0] = qv * A0.x; hh[1] = qv * A0.y; hh[2] = qv * A1.x; hh[3] = qv * A1.y;
    hh[4] = qv * B0.x; hh[5] = qv * B0.y; hh[6] = qv * B1.x; hh[7] = qv * B1.y;
    float cc = qv * kacc;
#pragma unroll
    for (int s = 1; s < 16; s <<= 1) {
#pragma unroll
        for (int j = 0; j < 8; j++) hh[j] += __shfl_xor(hh[j], s, 16);
        cc += __shfl_xor(cc, s, 16);
    }
    if ((lane & 15) < 8) {
        int j = lane & 7;
        float val = j < 4 ? (j < 2 ? (j == 0 ? hh[0] : hh[1]) : (j == 2 ? hh[2] : hh[3]))
                          : (j < 6 ? (j == 4 ? hh[4] : hh[5]) : (j == 6 ? hh[6] : hh[7]));
        size_t idx = (size_t)n * 32 + h * 8 + j;
        hid[idx] += gam * val / (cc + CSTF);
    }
}

// ---------------- final: out = hidden @ Wo + bo + teleport * teleportH ------

__global__ __launch_bounds__(256) void k_final(const float* __restrict__ hid,
    const float* __restrict__ Qg, const float* __restrict__ Wo,
    const float* __restrict__ bo, const float* __restrict__ tMK,
    const float* __restrict__ teleport, float* __restrict__ out) {
    __shared__ float tm[512];
    __shared__ float tk[64];
    __shared__ float wo[256];
    __shared__ float bos[8];
    int t = threadIdx.x;
    const float invN = 1.0f / (float)NN;
    for (int i = t; i < 512; i += 256) tm[i] = tMK[i] * invN;
    if (t < 64) tk[t] = tMK[512 + t] * invN;
    wo[t] = Wo[t & 255];
    if (t < 8) bos[t] = bo[t];
    __syncthreads();
    float tp = teleport[0];
    int lane = t & 63;
    int sub = lane & 7;
    int g = lane >> 3;
    int wid = (blockIdx.x * 256 + t) >> 6;
    int nwaves = gridDim.x * 4;
    for (int nb = wid * 8; nb < NN; nb += nwaves * 8) {
        int n = nb + g;
        if (n < NN) {
            const float* hrow = hid + (size_t)n * 32;
            const float* qrow = Qg + (size_t)n * 64;
            float o = bos[sub];
#pragma unroll
            for (int m = 0; m < 32; m++) o = fmaf(hrow[m], wo[m * 8 + sub], o);
            float th = 0.f;
#pragma unroll
            for (int h2 = 0; h2 < 4; h2++) {
                float num = 0.f, den = 0.f;
#pragma unroll
                for (int i = 0; i < 16; i++) {
                    float q = qrow[h2 * 16 + i];
                    num = fmaf(q, tm[h2 * 128 + i * 8 + sub], num);
                    den = fmaf(q, tk[h2 * 16 + i], den);
                }
                th += num / (den + CSTF);
            }
            out[(size_t)n * 8 + sub] = o + tp * th;
        }
    }
}

// ---------------- launch ----------------

extern "C" void kernel_launch(void* const* d_in, const int* in_sizes, int n_in,
                              void* d_out, int out_size, void* d_ws, size_t ws_size,
                              hipStream_t stream) {
    const float* nf = (const float*)d_in[0];
    const int* ei = (const int*)d_in[1];
    const float* Wi = (const float*)d_in[2];
    const float* bi = (const float*)d_in[3];
    const float* Wq = (const float*)d_in[4];
    const float* bq = (const float*)d_in[5];
    const float* Wk = (const float*)d_in[6];
    const float* bk = (const float*)d_in[7];
    const float* Wv = (const float*)d_in[8];
    const float* bv = (const float*)d_in[9];
    const float* Wo = (const float*)d_in[10];
    const float* bo = (const float*)d_in[11];
    const float* hopwise = (const float*)d_in[12];
    const float* headwise = (const float*)d_in[13];
    const float* teleport = (const float*)d_in[14];
    float* out = (float*)d_out;

    char* base = (char*)d_ws;
    size_t off = 0;
    auto alloc = [&](size_t bytes) -> void* {
        void* p = base + off;
        off = (off + bytes + 255) & ~(size_t)255;
        return p;
    };
    int* deg = (int*)alloc(NN * 4);
    int* cursor = (int*)alloc(NN * 4);
    int* offs = (int*)alloc((NN + 1) * 4);
    int* bsum = (int*)alloc(256 * 4);
    int* bex = (int*)alloc(256 * 4);
    float* dinv = (float*)alloc(NN * 4);
    int* csr_src = (int*)alloc((size_t)NE * 4);
    unsigned short* Wt = (unsigned short*)alloc(64 * 512 * 2);
    float* xbuf = (float*)alloc((size_t)NN * 64 * 4);
    float* Qg = (float*)alloc((size_t)NN * 64 * 4);
    float* hid = (float*)alloc((size_t)NN * 32 * 4);
    unsigned char* kv0 = (unsigned char*)alloc((size_t)NN * KVROW);
    unsigned char* S1 = (unsigned char*)alloc((size_t)NN * SROW);
    float* tMK = (float*)alloc(576 * 4);

    const int* rowp = ei;
    const int* colp = ei + NE;

    hipMemsetAsync(deg, 0, NN * 4, stream);

    k_deg_wt<<<(NE + 255) / 256, 256, 0, stream>>>(colp, deg, Wi, Wt);
    k_bsum<<<SCAN_NB, 256, 0, stream>>>(deg, bsum, dinv, cursor, tMK);
    k_bscan<<<1, 256, 0, stream>>>(bsum, bex);
    k_expand<<<SCAN_NB, 256, 0, stream>>>(deg, bex, offs);
    k_scatter<<<(NE + 255) / 256, 256, 0, stream>>>(rowp, colp, offs, cursor, csr_src);
    k_xgemm<<<XBLKS, 256, 0, stream>>>(nf, Wt, bi, xbuf);
    k_qkv<<<768, 256, 0, stream>>>(xbuf, Wq, bq, Wk, bk, Wv, bv, hopwise, dinv,
                                   Qg, hid, kv0, tMK);
    k_hop0<<<(NN * 64 + 255) / 256, 256, 0, stream>>>(kv0, offs, csr_src, dinv, Qg,
                                                      hopwise, headwise, S1, hid);
    k_prop1<<<(NN * 64 + 255) / 256, 256, 0, stream>>>(S1, offs, csr_src, Qg,
                                                       hopwise, headwise, hid);
    k_final<<<1563, 256, 0, stream>>>(hid, Qg, Wo, bo, tMK, teleport, out);
}